// Round 5
// baseline (361.011 us; speedup 1.0000x reference)
//
#include <hip/hip_runtime.h>

// Problem constants (from reference)
#define CC 9605
#define BB 2048
#define LL 8
#define CAND_MAX 512
#define NEGF (-1e30f)

// d_ws layout (unsigned words):
//   wsu[0] = wl entry count (atomic)
//   wsu[1] = dtype sniff flags (atomic OR)
//   wsu[2] = loss-block done counter (last block reduces)
//   wsu[4 .. 4+2048) = whitelist entries (col<<8 | mask)
//   byte offset 16384: float partials[BB]
#define WS_PARTIALS_OFF 16384

__device__ __forceinline__ unsigned enc_f(float f) {
  unsigned u = __float_as_uint(f);
  return (u & 0x80000000u) ? ~u : (u | 0x80000000u);
}
__device__ __forceinline__ float dec_u(unsigned e) {
  unsigned u = (e & 0x80000000u) ? (e & 0x7fffffffu) : ~e;
  return __uint_as_float(u);
}
__device__ __forceinline__ float sigm(float z) {
  return 1.0f / (1.0f + __expf(-z));
}

// ---- single setup kernel: dtype sniff + whitelist compaction ----
// dtype byte signatures (disjoint):
//   u8  : byte==1 at offsets %4 != 0        -> flag 1 (and 2)
//   i32 : byte==1 only at offsets %4 == 0   -> flag 2
//   f32 : 0x3f at %4==3, never byte==1      -> flag 8
//   bf16: 0x3f at odd offsets incl %4==1    -> flag 4 (and 8)
__global__ __launch_bounds__(1024) void wl_setup(
    const unsigned char* __restrict__ wl, unsigned* __restrict__ wsu) {
  __shared__ unsigned sh_flags;
  __shared__ unsigned sh_colmask[CC];
  const int tid = threadIdx.x;
  const int lane = tid & 63;
  if (tid == 0) sh_flags = 0u;
  // zero colmask
  for (int c = tid; c < CC; c += 1024) sh_colmask[c] = 0u;
  __syncthreads();

  // phase A: sniff dtype from raw words
  const unsigned* wlw = (const unsigned*)wl;
  const int nwords = (LL * CC) / 4;  // 76840 % 4 == 0
  unsigned f = 0u;
  for (int j = tid; j < nwords; j += 1024) {
    unsigned w = wlw[j];
#pragma unroll
    for (int k = 0; k < 4; ++k) {
      unsigned b = (w >> (8 * k)) & 255u;
      if (b == 1u)    { f |= 2u; if (k != 0) f |= 1u; }
      if (b == 0x3fu) { f |= 8u; if (k == 1) f |= 4u; }
    }
  }
#pragma unroll
  for (int off = 32; off >= 1; off >>= 1) f |= __shfl_xor(f, off, 64);
  if (lane == 0 && f) atomicOr(&sh_flags, f);
  __syncthreads();
  const unsigned g = sh_flags;
  const int dt = (g & 1u) ? 0 : (g & 4u) ? 3 : (g & 2u) ? 1 : (g & 8u) ? 2 : 0;

  // phase B: mark (label,col) hits into per-column bitmask (hits are rare)
  const int* wl32 = (const int*)wl;
  const float* wlf = (const float*)wl;
  const unsigned short* wlh = (const unsigned short*)wl;
  for (int e = tid; e < LL * CC; e += 1024) {
    bool on;
    if (dt == 0) on = (wl[e] != 0);
    else if (dt == 1) on = (wl32[e] != 0);
    else if (dt == 2) on = (wlf[e] != 0.0f);
    else on = (wlh[e] != 0);
    if (on) {
      int l = e / CC;          // compile-time magic-mul
      int c = e - l * CC;
      atomicOr(&sh_colmask[c], 1u << l);
    }
  }
  __syncthreads();

  // phase C: ballot-compact nonzero columns to global list
  for (int c0 = tid; c0 < CC + 1023; c0 += 1024) {
    unsigned m = (c0 < CC) ? sh_colmask[c0] : 0u;
    unsigned long long bal = __ballot(m != 0u);
    if (bal) {
      unsigned wcnt = (unsigned)__popcll(bal);
      unsigned basep = 0u;
      if (lane == 0) basep = atomicAdd(&wsu[0], wcnt);
      basep = __shfl(basep, 0, 64);
      if (m) {
        unsigned pos = basep + (unsigned)__popcll(bal & ((1ull << lane) - 1ull));
        if (pos < 2048u) wsu[4 + pos] = ((unsigned)c0 << 8) | m;
      }
    }
  }
}

__global__ __launch_bounds__(256, 4) void loss_kernel(
    const float* __restrict__ x, const float* __restrict__ y,
    unsigned* __restrict__ wsu, float* __restrict__ partials,
    float* __restrict__ out) {
  __shared__ __align__(16) unsigned sh_row[9608];  // padded to 2402 uint4
  __shared__ unsigned sh_cand[CAND_MAX];
  __shared__ unsigned sh_redM[4];
  __shared__ unsigned sh_redC[4];
  __shared__ unsigned sh_cnt;
  __shared__ unsigned sh_e11;
  __shared__ unsigned sh_last;
  __shared__ float sh_wl[4][10];
  __shared__ float sh_fin[4];

  const int tid = threadIdx.x;
  const int lane = tid & 63;
  const int wid = tid >> 6;
  const int b = blockIdx.x;
  const long long base = (long long)b * CC;

  // ---- 1. stage row -> LDS (encoded), track max on the fly ----
  const int soff = (4 - (b & 3)) & 3;          // (b*9605 + soff) % 4 == 0
  const int ngroups = (CC - soff) >> 2;        // 2400 or 2401
  const int tailn = CC - soff - (ngroups << 2);
  const int m_extra = soff + tailn;            // <= 6 scalar leftovers
  const float4* vp = (const float4*)(x + base + soff);  // 16B aligned
  uint4* rv = (uint4*)sh_row;
  unsigned mx = 0u;
#pragma unroll
  for (int i = 0; i < 9; ++i) {                // g <= 2303 < 2400: no bound
    int g = tid + (i << 8);
    float4 v = vp[g];
    uint4 e;
    e.x = enc_f(v.x); e.y = enc_f(v.y); e.z = enc_f(v.z); e.w = enc_f(v.w);
    mx = max(mx, max(max(e.x, e.y), max(e.z, e.w)));
    rv[g] = e;
  }
  {
    int g = tid + (9 << 8);
    if (g < ngroups) {
      float4 v = vp[g];
      uint4 e;
      e.x = enc_f(v.x); e.y = enc_f(v.y); e.z = enc_f(v.z); e.w = enc_f(v.w);
      mx = max(mx, max(max(e.x, e.y), max(e.z, e.w)));
      rv[g] = e;
    }
  }
  if (tid < m_extra) {
    int col = (tid < soff) ? tid : (soff + (ngroups << 2) + (tid - soff));
    unsigned e = enc_f(x[base + col]);
    mx = max(mx, e);
    sh_row[(ngroups << 2) + tid] = e;
  }
  if (tid < 3) sh_row[9605 + tid] = 0u;        // pad (enc 0 < any real value)
  if (tid == 0) sh_cnt = 0u;

  // ---- 2. block max ----
#pragma unroll
  for (int off = 32; off >= 1; off >>= 1) mx = max(mx, __shfl_xor(mx, off, 64));
  if (lane == 0) sh_redM[wid] = mx;
  __syncthreads();                              // also fences staging writes
  const unsigned Emax =
      max(max(sh_redM[0], sh_redM[1]), max(sh_redM[2], sh_redM[3]));

  // block count of row >= T from LDS (uniform result)
  auto blk_count = [&](unsigned T) -> unsigned {
    unsigned cnt = 0u;
#pragma unroll
    for (int i = 0; i < 10; ++i) {
      int g = tid + (i << 8);
      if (g < 2402) {
        uint4 v = rv[g];
        cnt += (v.x >= T) + (v.y >= T) + (v.z >= T) + (v.w >= T);
      }
    }
#pragma unroll
    for (int off = 32; off >= 1; off >>= 1) cnt += __shfl_xor(cnt, off, 64);
    __syncthreads();                            // guard sh_redC reuse
    if (lane == 0) sh_redC[wid] = cnt;
    __syncthreads();
    return sh_redC[0] + sh_redC[1] + sh_redC[2] + sh_redC[3];
  };

  // ---- 3. find window [lo,...] holding rank 11 (typ. 1 probe) ----
  unsigned E11 = 0u;
  bool done = false;
  unsigned lo = (Emax > (1u << 23)) ? (Emax - (1u << 23)) : 1u;
  unsigned hi = Emax + 1u;
  unsigned c = blk_count(lo);
  while (c < 11u && lo > 1u) {
    hi = lo;
    lo = (lo > (1u << 23)) ? (lo - (1u << 23)) : 1u;
    c = blk_count(lo);
  }
  while (c > CAND_MAX) {  // rare: bisect (tie-collapse => exact answer)
    if (hi - lo <= 1u) { E11 = lo; done = true; break; }
    unsigned mid = lo + ((hi - lo) >> 1);
    unsigned cm = blk_count(mid);
    if (cm >= 11u) { lo = mid; c = cm; } else { hi = mid; }
  }

  // ---- 4. ballot-compact candidates (>= lo) into sh_cand ----
  if (!done) {
#pragma unroll
    for (int i = 0; i < 10; ++i) {
      int g = tid + (i << 8);
      uint4 v;
      if (g < 2402) v = rv[g];
      else { v.x = 0u; v.y = 0u; v.z = 0u; v.w = 0u; }
      unsigned vals[4] = {v.x, v.y, v.z, v.w};
#pragma unroll
      for (int k = 0; k < 4; ++k) {
        bool pr = (vals[k] >= lo);
        unsigned long long bal = __ballot(pr);
        if (bal) {
          unsigned wcnt = (unsigned)__popcll(bal);
          unsigned basep = 0u;
          if (lane == 0) basep = atomicAdd(&sh_cnt, wcnt);
          basep = __shfl(basep, 0, 64);
          if (pr) {
            unsigned posn =
                basep + (unsigned)__popcll(bal & ((1ull << lane) - 1ull));
            sh_cand[posn] = vals[k];
          }
        }
      }
    }
    __syncthreads();

    // ---- 5. single-wave register top-11 (no LDS latency, no barriers) ----
    if (wid == 0) {
      unsigned v0[8];
#pragma unroll
      for (int j = 0; j < 8; ++j) {
        unsigned idx = (unsigned)lane + 64u * j;
        v0[j] = (idx < c) ? sh_cand[idx] : 0u;
      }
      unsigned ans = 0u;
      for (int r = 0; r < 11; ++r) {
        unsigned lmx = v0[0];
#pragma unroll
        for (int j = 1; j < 8; ++j) lmx = max(lmx, v0[j]);
        unsigned wm = lmx;
#pragma unroll
        for (int off = 32; off >= 1; off >>= 1)
          wm = max(wm, __shfl_xor(wm, off, 64));
        ans = wm;
        if (r < 10) {
          unsigned long long bal = __ballot(lmx == wm);
          int first = (int)__ffsll((long long)bal) - 1;
          if (lane == first) {  // remove ONE instance of wm
            bool rm = false;
#pragma unroll
            for (int j = 0; j < 8; ++j) {
              if (!rm && v0[j] == wm) { v0[j] = 0u; rm = true; }
            }
          }
        }
      }
      if (lane == 0) sh_e11 = ans;
    }
    __syncthreads();
    E11 = sh_e11;
  }

  // ---- 6. whitelist gather: per-label max + masks ----
  const unsigned nu = wsu[0];
  const unsigned* ents = wsu + 4;
  float lm[8];
#pragma unroll
  for (int l = 0; l < 8; ++l) lm[l] = NEGF;
  unsigned pmask = 0u;  // bits0-7: label present; bits8-15: label has positive
  for (unsigned e = tid; e < nu; e += 256u) {
    unsigned ent = ents[e];
    unsigned ccol = ent >> 8;
    unsigned mk = ent & 255u;
    float xv = x[base + (long long)ccol];
    float yv = y[base + (long long)ccol];
    pmask |= mk;
    if (yv > 0.0f) pmask |= (mk << 8);
#pragma unroll
    for (int l = 0; l < 8; ++l)
      if ((mk >> l) & 1u) lm[l] = fmaxf(lm[l], xv);
  }
#pragma unroll
  for (int off = 32; off >= 1; off >>= 1) {
    pmask |= __shfl_xor(pmask, off, 64);
#pragma unroll
    for (int l = 0; l < 8; ++l) lm[l] = fmaxf(lm[l], __shfl_xor(lm[l], off, 64));
  }
  if (lane == 0) {
#pragma unroll
    for (int l = 0; l < 8; ++l) sh_wl[wid][l] = lm[l];
    sh_wl[wid][8] = __uint_as_float(pmask);
  }
  __syncthreads();

  // ---- 7. epilogue on thread 0: per-row value + done-count ----
  if (tid == 0) {
    float LM[8];
    unsigned PM = 0u;
#pragma unroll
    for (int l = 0; l < 8; ++l) LM[l] = NEGF;
    for (int w = 0; w < 4; ++w) {
#pragma unroll
      for (int l = 0; l < 8; ++l) LM[l] = fmaxf(LM[l], sh_wl[w][l]);
      PM |= __float_as_uint(sh_wl[w][8]);
    }
    unsigned PR = PM & 255u, PO = (PM >> 8) & 255u;
    float thres = fmaxf(sigm(dec_u(E11)), 0.5f);
    float cmax = NEGF, imax = NEGF, umax = NEGF;
#pragma unroll
    for (int l = 0; l < 8; ++l) {
      if ((PR >> l) & 1u) {
        float ml = sigm(LM[l]);
        umax = fmaxf(umax, ml);
        if ((PO >> l) & 1u) cmax = fmaxf(cmax, ml);
        else imax = fmaxf(imax, ml);
      }
    }
    bool anyc = (PO != 0u);
    bool anyi = (PO != 255u);  // L == 8 labels always exist
    float x1 = anyc ? cmax : thres;
    float x2 = anyc ? (anyi ? fmaxf(imax, thres) : thres)
                    : ((nu > 0u) ? umax : NEGF);
    float coef = anyc ? 1.0f : 0.5f;
    float dd = x2 - x1 + 0.1f;
    float rank = ((dd > 0.0f) ? 2.0f : 1.0f) * sigm(10.0f * dd);
    partials[b] = coef * rank;
    __threadfence();
    unsigned old = atomicAdd(&wsu[2], 1u);
    sh_last = (old == (unsigned)(BB - 1)) ? 1u : 0u;
  }
  __syncthreads();

  // ---- 8. last block reduces partials -> out ----
  if (sh_last) {
    __threadfence();
    float s = 0.0f;
    for (int i = tid; i < BB; i += 256) s += partials[i];
#pragma unroll
    for (int off = 32; off >= 1; off >>= 1) s += __shfl_xor(s, off, 64);
    if (lane == 0) sh_fin[wid] = s;
    __syncthreads();
    if (tid == 0)
      out[0] = (sh_fin[0] + sh_fin[1] + sh_fin[2] + sh_fin[3]) * (1.0f / (float)BB);
  }
}

extern "C" void kernel_launch(void* const* d_in, const int* in_sizes, int n_in,
                              void* d_out, int out_size, void* d_ws,
                              size_t ws_size, hipStream_t stream) {
  const float* x = (const float*)d_in[0];
  const float* y = (const float*)d_in[1];
  // d_in[2] (y_neg) is faithfully ignored — it never affects the loss.
  const unsigned char* wl = (const unsigned char*)d_in[3];
  float* out = (float*)d_out;
  unsigned* wsu = (unsigned*)d_ws;
  float* partials = (float*)((char*)d_ws + WS_PARTIALS_OFF);

  hipMemsetAsync(d_ws, 0, 16, stream);  // zero wsu[0..3]
  wl_setup<<<1, 1024, 0, stream>>>(wl, wsu);
  loss_kernel<<<BB, 256, 0, stream>>>(x, y, wsu, partials, out);
}

// Round 6
// 232.030 us; speedup vs baseline: 1.5559x; 1.5559x over previous
//
#include <hip/hip_runtime.h>

// Problem constants (from reference)
#define CC 9605
#define BB 2048
#define LL 8
#define CAND_MAX 384
#define NEGF (-1e30f)

// d_ws layout (unsigned words):
//   wsu[0] = wl entry count (atomic)
//   wsu[1] = dtype sniff flags (atomic OR)
//   wsu[4 .. 4+2048) = whitelist entries (col<<8 | mask)
//   byte offset 16384: float partials[BB]
#define WS_PARTIALS_OFF 16384

__device__ __forceinline__ unsigned enc_f(float f) {
  unsigned u = __float_as_uint(f);
  return (u & 0x80000000u) ? ~u : (u | 0x80000000u);
}
__device__ __forceinline__ float dec_u(unsigned e) {
  unsigned u = (e & 0x80000000u) ? (e & 0x7fffffffu) : ~e;
  return __uint_as_float(u);
}
__device__ __forceinline__ float sigm(float z) {
  return 1.0f / (1.0f + __expf(-z));
}

// ---- dtype sniff (word loads): byte signatures over the raw wl buffer ----
//   u8  : byte==1 at offsets %4 != 0        -> flag 1 (and 2)
//   i32 : byte==1 only at offsets %4 == 0   -> flag 2
//   f32 : 0x3f at %4==3, never byte==1      -> flag 8
//   bf16: 0x3f at odd offsets incl %4==1    -> flag 4 (and 8)
__global__ void wl_sniff(const unsigned* __restrict__ wlw,
                         unsigned* __restrict__ wsu) {
  const int nwords = (LL * CC) / 4;  // 76840 % 4 == 0
  const int stride = gridDim.x * blockDim.x;
  unsigned f = 0u;
  for (int j = blockIdx.x * blockDim.x + threadIdx.x; j < nwords; j += stride) {
    unsigned w = wlw[j];
#pragma unroll
    for (int k = 0; k < 4; ++k) {
      unsigned b = (w >> (8 * k)) & 255u;
      if (b == 1u)    { f |= 2u; if (k != 0) f |= 1u; }
      if (b == 0x3fu) { f |= 8u; if (k == 1) f |= 4u; }
    }
  }
#pragma unroll
  for (int off = 32; off >= 1; off >>= 1) f |= __shfl_xor(f, off, 64);
  if ((threadIdx.x & 63) == 0 && f) atomicOr(&wsu[1], f);
}

__global__ void wl_compact(const unsigned char* __restrict__ wl,
                           unsigned* __restrict__ wsu) {
  const int tid = threadIdx.x;
  const int lane = tid & 63;
  const int c = blockIdx.x * 256 + tid;
  const unsigned g = wsu[1];
  const int dt = (g & 1u) ? 0 : (g & 4u) ? 3 : (g & 2u) ? 1 : (g & 8u) ? 2 : 0;
  const int* wl32 = (const int*)wl;
  const float* wlf = (const float*)wl;
  const unsigned short* wlh = (const unsigned short*)wl;
  unsigned m = 0u;
  if (c < CC) {
#pragma unroll
    for (int l = 0; l < LL; ++l) {
      int j = l * CC + c;
      bool on;
      if (dt == 0) on = (wl[j] != 0);
      else if (dt == 1) on = (wl32[j] != 0);
      else if (dt == 2) on = (wlf[j] != 0.0f);
      else on = (wlh[j] != 0);
      if (on) m |= (1u << l);
    }
  }
  unsigned long long bal = __ballot(m != 0u);
  if (bal) {
    unsigned wcnt = (unsigned)__popcll(bal);
    unsigned basep = 0u;
    if (lane == 0) basep = atomicAdd(&wsu[0], wcnt);
    basep = __shfl(basep, 0, 64);
    if (m) {
      unsigned pos = basep + (unsigned)__popcll(bal & ((1ull << lane) - 1ull));
      if (pos < 2048u) wsu[4 + pos] = ((unsigned)c << 8) | m;
    }
  }
}

__global__ __launch_bounds__(256, 4) void loss_kernel(
    const float* __restrict__ x, const float* __restrict__ y,
    const unsigned* __restrict__ wsu, float* __restrict__ partials) {
  __shared__ __align__(16) unsigned sh_row[9608];  // 2402 uint4 (row + pad)
  __shared__ unsigned sh_cand[CAND_MAX];
  __shared__ unsigned sh_redM[4];
  __shared__ unsigned sh_redC[4];
  __shared__ unsigned sh_cnt;
  __shared__ unsigned sh_e11;
  __shared__ float sh_wl[4][10];

  const int tid = threadIdx.x;
  const int lane = tid & 63;
  const int wid = tid >> 6;
  const int b = blockIdx.x;
  const long long base = (long long)b * CC;

  // ---- 1a. issue ALL row loads first (max memory-level parallelism) ----
  const int soff = (4 - (b & 3)) & 3;          // (b*9605 + soff) % 4 == 0
  const int ngroups = (CC - soff) >> 2;        // 2400 or 2401
  const int tailn = CC - soff - (ngroups << 2);
  const int m_extra = soff + tailn;            // <= 6 scalar leftovers
  const float4* vp = (const float4*)(x + base + soff);  // 16B aligned
  float4 t[10];
#pragma unroll
  for (int i = 0; i < 9; ++i) t[i] = vp[tid + (i << 8)];  // g <= 2303 < 2400
  const int g9 = tid + (9 << 8);
  if (g9 < ngroups) t[9] = vp[g9];
  else { t[9].x = NEGF; t[9].y = NEGF; t[9].z = NEGF; t[9].w = NEGF; }
  float tailv = NEGF;
  int tailcol = 0;
  if (tid < m_extra) {
    tailcol = (tid < soff) ? tid : (soff + (ngroups << 2) + (tid - soff));
    tailv = x[base + tailcol];
  }

  // ---- 1b. issue whitelist gather loads early (latency hides under
  //          the LDS-only selection phase below) ----
  const unsigned nu = wsu[0];
  const unsigned* ents = wsu + 4;
  unsigned ent0 = 0u, ent1 = 0u;
  float gx0 = NEGF, gy0 = 0.0f, gx1 = NEGF, gy1 = 0.0f;
  const bool h0 = (unsigned)tid < nu;
  const bool h1 = (unsigned)(tid + 256) < nu;
  if (h0) ent0 = ents[tid];
  if (h1) ent1 = ents[tid + 256];
  if (h0) { gx0 = x[base + (ent0 >> 8)]; gy0 = y[base + (ent0 >> 8)]; }
  if (h1) { gx1 = x[base + (ent1 >> 8)]; gy1 = y[base + (ent1 >> 8)]; }

  // ---- 1c. encode + stage row into LDS, track max ----
  uint4* rv = (uint4*)sh_row;
  unsigned mx = 0u;
#pragma unroll
  for (int i = 0; i < 10; ++i) {
    int g = tid + (i << 8);
    uint4 e;
    e.x = enc_f(t[i].x); e.y = enc_f(t[i].y);
    e.z = enc_f(t[i].z); e.w = enc_f(t[i].w);
    if (i < 9 || g < ngroups) {
      mx = max(mx, max(max(e.x, e.y), max(e.z, e.w)));
      rv[g] = e;
    }
  }
  if (tid < m_extra) {
    unsigned e = enc_f(tailv);
    mx = max(mx, e);
    sh_row[(ngroups << 2) + tid] = e;
  }
  if (tid < 3) sh_row[9605 + tid] = 0u;        // pad (enc 0 < any real value)
  if (tid == 0) sh_cnt = 0u;

  // ---- 2. block max ----
#pragma unroll
  for (int off = 32; off >= 1; off >>= 1) mx = max(mx, __shfl_xor(mx, off, 64));
  if (lane == 0) sh_redM[wid] = mx;
  __syncthreads();                              // fences staging writes
  const unsigned Emax =
      max(max(sh_redM[0], sh_redM[1]), max(sh_redM[2], sh_redM[3]));

  // block count of row >= T from LDS (uniform result)
  auto blk_count = [&](unsigned T) -> unsigned {
    unsigned cnt = 0u;
#pragma unroll
    for (int i = 0; i < 10; ++i) {
      int g = tid + (i << 8);
      if (g < 2402) {
        uint4 v = rv[g];
        cnt += (v.x >= T) + (v.y >= T) + (v.z >= T) + (v.w >= T);
      }
    }
#pragma unroll
    for (int off = 32; off >= 1; off >>= 1) cnt += __shfl_xor(cnt, off, 64);
    __syncthreads();                            // guard sh_redC reuse
    if (lane == 0) sh_redC[wid] = cnt;
    __syncthreads();
    return sh_redC[0] + sh_redC[1] + sh_redC[2] + sh_redC[3];
  };

  // ---- 3. find window [lo,...] holding rank 11 (typ. 1 probe) ----
  unsigned E11 = 0u;
  bool done = false;
  unsigned lo = (Emax > (1u << 23)) ? (Emax - (1u << 23)) : 1u;
  unsigned hi = Emax + 1u;
  unsigned c = blk_count(lo);
  while (c < 11u && lo > 1u) {
    hi = lo;
    lo = (lo > (1u << 23)) ? (lo - (1u << 23)) : 1u;
    c = blk_count(lo);
  }
  while (c > CAND_MAX) {  // rare: bisect (tie-collapse => exact answer)
    if (hi - lo <= 1u) { E11 = lo; done = true; break; }
    unsigned mid = lo + ((hi - lo) >> 1);
    unsigned cm = blk_count(mid);
    if (cm >= 11u) { lo = mid; c = cm; } else { hi = mid; }
  }

  // ---- 4. ballot-compact candidates (>= lo) into sh_cand ----
  if (!done) {
#pragma unroll
    for (int i = 0; i < 10; ++i) {
      int g = tid + (i << 8);
      uint4 v;
      if (g < 2402) v = rv[g];
      else { v.x = 0u; v.y = 0u; v.z = 0u; v.w = 0u; }
      unsigned vals[4] = {v.x, v.y, v.z, v.w};
#pragma unroll
      for (int k = 0; k < 4; ++k) {
        bool pr = (vals[k] >= lo);
        unsigned long long bal = __ballot(pr);
        if (bal) {
          unsigned wcnt = (unsigned)__popcll(bal);
          unsigned basep = 0u;
          if (lane == 0) basep = atomicAdd(&sh_cnt, wcnt);
          basep = __shfl(basep, 0, 64);
          if (pr) {
            unsigned posn =
                basep + (unsigned)__popcll(bal & ((1ull << lane) - 1ull));
            sh_cand[posn] = vals[k];
          }
        }
      }
    }
    __syncthreads();

    // ---- 5. single-wave register top-11 (no barriers, no LDS latency) ----
    if (wid == 0) {
      unsigned v0[6];                           // 6*64 = 384 = CAND_MAX
#pragma unroll
      for (int j = 0; j < 6; ++j) {
        unsigned idx = (unsigned)lane + 64u * j;
        v0[j] = (idx < c) ? sh_cand[idx] : 0u;
      }
      unsigned ans = 0u;
      for (int r = 0; r < 11; ++r) {
        unsigned lmx = v0[0];
#pragma unroll
        for (int j = 1; j < 6; ++j) lmx = max(lmx, v0[j]);
        unsigned wm = lmx;
#pragma unroll
        for (int off = 32; off >= 1; off >>= 1)
          wm = max(wm, __shfl_xor(wm, off, 64));
        ans = wm;
        if (r < 10) {
          unsigned long long bal = __ballot(lmx == wm);
          int first = (int)__ffsll((long long)bal) - 1;
          if (lane == first) {  // remove ONE instance of wm
            bool rm = false;
#pragma unroll
            for (int j = 0; j < 6; ++j) {
              if (!rm && v0[j] == wm) { v0[j] = 0u; rm = true; }
            }
          }
        }
      }
      if (lane == 0) sh_e11 = ans;
    }
    __syncthreads();
    E11 = sh_e11;
  }

  // ---- 6. whitelist gather accumulate (loads issued in 1b, long arrived) ----
  float lm[8];
#pragma unroll
  for (int l = 0; l < 8; ++l) lm[l] = NEGF;
  unsigned pmask = 0u;  // bits0-7: label present; bits8-15: label has positive
  if (h0) {
    unsigned mk = ent0 & 255u;
    pmask |= mk;
    if (gy0 > 0.0f) pmask |= (mk << 8);
#pragma unroll
    for (int l = 0; l < 8; ++l)
      if ((mk >> l) & 1u) lm[l] = fmaxf(lm[l], gx0);
  }
  if (h1) {
    unsigned mk = ent1 & 255u;
    pmask |= mk;
    if (gy1 > 0.0f) pmask |= (mk << 8);
#pragma unroll
    for (int l = 0; l < 8; ++l)
      if ((mk >> l) & 1u) lm[l] = fmaxf(lm[l], gx1);
  }
  // safety net (nu <= 400 in this problem; loop normally never runs)
  for (unsigned e = (unsigned)tid + 512u; e < nu; e += 256u) {
    unsigned ent = ents[e];
    unsigned mk = ent & 255u;
    float xv = x[base + (ent >> 8)];
    float yv = y[base + (ent >> 8)];
    pmask |= mk;
    if (yv > 0.0f) pmask |= (mk << 8);
#pragma unroll
    for (int l = 0; l < 8; ++l)
      if ((mk >> l) & 1u) lm[l] = fmaxf(lm[l], xv);
  }
#pragma unroll
  for (int off = 32; off >= 1; off >>= 1) {
    pmask |= __shfl_xor(pmask, off, 64);
#pragma unroll
    for (int l = 0; l < 8; ++l) lm[l] = fmaxf(lm[l], __shfl_xor(lm[l], off, 64));
  }
  if (lane == 0) {
#pragma unroll
    for (int l = 0; l < 8; ++l) sh_wl[wid][l] = lm[l];
    sh_wl[wid][8] = __uint_as_float(pmask);
  }
  __syncthreads();

  // ---- 7. epilogue on thread 0: per-row partial (no fences, no atomics) ----
  if (tid == 0) {
    float LM[8];
    unsigned PM = 0u;
#pragma unroll
    for (int l = 0; l < 8; ++l) LM[l] = NEGF;
    for (int w = 0; w < 4; ++w) {
#pragma unroll
      for (int l = 0; l < 8; ++l) LM[l] = fmaxf(LM[l], sh_wl[w][l]);
      PM |= __float_as_uint(sh_wl[w][8]);
    }
    unsigned PR = PM & 255u, PO = (PM >> 8) & 255u;
    float thres = fmaxf(sigm(dec_u(E11)), 0.5f);
    float cmax = NEGF, imax = NEGF, umax = NEGF;
#pragma unroll
    for (int l = 0; l < 8; ++l) {
      if ((PR >> l) & 1u) {
        float ml = sigm(LM[l]);
        umax = fmaxf(umax, ml);
        if ((PO >> l) & 1u) cmax = fmaxf(cmax, ml);
        else imax = fmaxf(imax, ml);
      }
    }
    bool anyc = (PO != 0u);
    bool anyi = (PO != 255u);  // L == 8 labels always exist
    float x1 = anyc ? cmax : thres;
    float x2 = anyc ? (anyi ? fmaxf(imax, thres) : thres)
                    : ((nu > 0u) ? umax : NEGF);
    float coef = anyc ? 1.0f : 0.5f;
    float dd = x2 - x1 + 0.1f;
    float rank = ((dd > 0.0f) ? 2.0f : 1.0f) * sigm(10.0f * dd);
    partials[b] = coef * rank;
  }
}

__global__ void final_reduce(const float* __restrict__ partials,
                             float* __restrict__ out) {
  __shared__ float sh[4];
  const int tid = threadIdx.x;
  const int lane = tid & 63;
  const int wid = tid >> 6;
  float s = 0.0f;
  for (int i = tid; i < BB; i += 256) s += partials[i];
#pragma unroll
  for (int off = 32; off >= 1; off >>= 1) s += __shfl_xor(s, off, 64);
  if (lane == 0) sh[wid] = s;
  __syncthreads();
  if (tid == 0) out[0] = (sh[0] + sh[1] + sh[2] + sh[3]) * (1.0f / (float)BB);
}

extern "C" void kernel_launch(void* const* d_in, const int* in_sizes, int n_in,
                              void* d_out, int out_size, void* d_ws,
                              size_t ws_size, hipStream_t stream) {
  const float* x = (const float*)d_in[0];
  const float* y = (const float*)d_in[1];
  // d_in[2] (y_neg) is faithfully ignored — it never affects the loss.
  const unsigned char* wl = (const unsigned char*)d_in[3];
  float* out = (float*)d_out;
  unsigned* wsu = (unsigned*)d_ws;
  float* partials = (float*)((char*)d_ws + WS_PARTIALS_OFF);

  hipMemsetAsync(d_ws, 0, 16, stream);  // zero wsu[0..3]
  wl_sniff<<<64, 256, 0, stream>>>((const unsigned*)wl, wsu);
  wl_compact<<<(CC + 255) / 256, 256, 0, stream>>>(wl, wsu);
  loss_kernel<<<BB, 256, 0, stream>>>(x, y, wsu, partials);
  final_reduce<<<1, 256, 0, stream>>>(partials, out);
}